// Round 12
// baseline (2831.652 us; speedup 1.0000x reference)
//
#include <hip/hip_runtime.h>

// ===========================================================================
// GAT_CNN_DASE :: gfx950 :: R12.
// R11: 2721 us; L1 mgemm ~228 us/chunk, memory/latency-bound on feats
// re-reads (11 N-tiles), MfmaUtil 23%, VALUBusy 12%.
// R12: L1 -> fp8 e4m3 MFMA (16x16x32_fp8_fp8), BK=64 (half the barriers),
// half the staging bytes. feats q = feats*2^-9 (sat 448), W1 q = W1*64,
// epilogue acc*8 (+bias, lrelu) -> exact scale restore (lrelu pos-homog).
// L2/L3 GEMMs stay bf16 (unchanged). Front end unchanged.
// ===========================================================================

typedef unsigned short u16;
typedef unsigned char u8;
typedef __attribute__((ext_vector_type(8))) short bf16x8;
typedef __attribute__((ext_vector_type(4))) float f32x4;
typedef __attribute__((ext_vector_type(4))) unsigned int u32x4;

__device__ __forceinline__ float b2f(u16 u) {
  unsigned v = ((unsigned)u) << 16;
  return __builtin_bit_cast(float, v);
}
__device__ __forceinline__ u16 f2b(float f) {
  unsigned x = __builtin_bit_cast(unsigned, f);
  x += 0x7fffu + ((x >> 16) & 1u);
  return (u16)(x >> 16);
}

// float -> OCP e4m3fn, RNE, saturating to +-448. Never emits NaN for finite f.
__device__ __forceinline__ u8 q8(float f) {
  unsigned u = __builtin_bit_cast(unsigned, f);
  unsigned s = (u >> 24) & 0x80u;
  float a = fabsf(f);
  if (!(a == a)) return (u8)(s | 0x7E);  // NaN input -> max (defensive)
  if (a > 448.f) a = 448.f;
  u8 r;
  if (a < 0.0009765625f) {  // < 2^-10 -> 0
    r = 0;
  } else if (a < 0.001953125f) {  // [2^-10, 2^-9) -> min subnormal
    r = 1;
  } else {
    unsigned bits = __builtin_bit_cast(unsigned, a);
    int exp = ((bits >> 23) & 0xFF) - 127;
    if (exp < -6) {  // subnormal: units of 2^-9
      float q = a * 512.f;
      int m = (int)(q + 0.5f);
      r = (m > 7) ? (u8)0x08 : (u8)m;
    } else {
      unsigned mant = (bits >> 20) & 0x7u;
      unsigned rest = bits & 0xFFFFFu;
      unsigned v = (((unsigned)(exp + 7)) << 3) | mant;
      if (rest > 0x80000u || (rest == 0x80000u && (mant & 1u))) v++;
      if (v > 0x7Eu) v = 0x7Eu;  // cap at 448
      r = (u8)v;
    }
  }
  return (u8)(r | s);
}

// async global->LDS, 16B per lane; LDS dest = wave-uniform base + lane*16
__device__ __forceinline__ void async_ld16(const void* g, void* l) {
  __builtin_amdgcn_global_load_lds(
      (const __attribute__((address_space(1))) void*)g,
      (__attribute__((address_space(3))) void*)l, 16, 0, 0);
}

// bf16 data: ~100% of u16s have exponent in [100,140]; f32-as-u16: ~58%.
__device__ __forceinline__ int sniff_bf16(const void* p, int n) {
  const u16* pu = (const u16*)p;
  int ns = n < 128 ? n : 128;
  int sane = 0, nz = 0;
  for (int i = 0; i < ns; i++) {
    u16 v = pu[i];
    if (v) nz++;
    int e = (v >> 7) & 0xFF;
    if (e >= 100 && e <= 140) sane++;
  }
  return (nz == 0) || (sane * 8 >= ns * 7);
}
__device__ __forceinline__ float ld_any(const void* p, size_t i, int isbf) {
  return isbf ? b2f(((const u16*)p)[i]) : ((const float*)p)[i];
}

__global__ void cvt_f(const void* __restrict__ in, float* __restrict__ out,
                      int n) {
  __shared__ int sbf;
  if (threadIdx.x == 0) sbf = sniff_bf16(in, n);
  __syncthreads();
  int tid = blockIdx.x * 256 + threadIdx.x;
  if (tid < n) out[tid] = ld_any(in, tid, sbf);
}
__global__ void cvt_f_t(const void* __restrict__ in, float* __restrict__ out,
                        int K, int N) {
  __shared__ int sbf;
  if (threadIdx.x == 0) sbf = sniff_bf16(in, K * N);
  __syncthreads();
  int tid = blockIdx.x * 256 + threadIdx.x;
  if (tid >= K * N) return;
  int nn = tid / K, k = tid - nn * K;
  out[tid] = ld_any(in, (size_t)k * N + nn, sbf);
}
__global__ void cvt_b(const void* __restrict__ in, u16* __restrict__ out,
                      int n) {
  __shared__ int sbf;
  if (threadIdx.x == 0) sbf = sniff_bf16(in, n);
  __syncthreads();
  int tid = blockIdx.x * 256 + threadIdx.x;
  if (tid < n) out[tid] = f2b(ld_any(in, tid, sbf));
}
// tiled transpose-convert: in K x N -> out Npad x Kpad bf16, zero-padded.
__global__ void cvt_b_tt(const void* __restrict__ in, u16* __restrict__ out,
                         int K, int N, int Kpad, int Npad) {
  __shared__ int sbf;
  __shared__ float tile[32][33];
  if (threadIdx.x == 0) sbf = sniff_bf16(in, K * N);
  __syncthreads();
  int k0 = blockIdx.x * 32, n0 = blockIdx.y * 32;
  int tx = threadIdx.x & 31, ty = threadIdx.x >> 5;
#pragma unroll
  for (int i = 0; i < 32; i += 8) {
    int k = k0 + ty + i, n = n0 + tx;
    tile[ty + i][tx] =
        (k < K && n < N) ? ld_any(in, (size_t)k * N + n, sbf) : 0.f;
  }
  __syncthreads();
#pragma unroll
  for (int i = 0; i < 32; i += 8) {
    int n = n0 + ty + i, k = k0 + tx;
    if (n < Npad && k < Kpad) out[(size_t)n * Kpad + k] = f2b(tile[tx][ty + i]);
  }
}
// tiled transpose-convert to fp8 with scale: out Npad x Kpad u8, zero-padded.
__global__ void cvt_q_tt(const void* __restrict__ in, u8* __restrict__ out,
                         int K, int N, int Kpad, int Npad, float scale) {
  __shared__ int sbf;
  __shared__ float tile[32][33];
  if (threadIdx.x == 0) sbf = sniff_bf16(in, K * N);
  __syncthreads();
  int k0 = blockIdx.x * 32, n0 = blockIdx.y * 32;
  int tx = threadIdx.x & 31, ty = threadIdx.x >> 5;
#pragma unroll
  for (int i = 0; i < 32; i += 8) {
    int k = k0 + ty + i, n = n0 + tx;
    tile[ty + i][tx] =
        (k < K && n < N) ? ld_any(in, (size_t)k * N + n, sbf) * scale : 0.f;
  }
  __syncthreads();
#pragma unroll
  for (int i = 0; i < 32; i += 8) {
    int n = n0 + ty + i, k = k0 + tx;
    if (n < Npad && k < Kpad) out[(size_t)n * Kpad + k] = q8(tile[tx][ty + i]);
  }
}

// ---------------------------------------------------------------------------
// feats chunk, fp8: fq[r][k] = e4m3(emb[p0]*emb[1500+p1] * 2^-9), stride 2816
// (cols 2778..2816 zero). One thread per 16 elements.
// ---------------------------------------------------------------------------
__global__ void k_feats_q(const u16* __restrict__ emb,
                          const int* __restrict__ posp,
                          const int* __restrict__ negp, int npos, int mbase,
                          int rows, u8* __restrict__ fq) {
  int idx = blockIdx.x * 256 + threadIdx.x;
  int r = idx / 176, c16 = idx - r * 176;
  if (r >= rows) return;
  int cb = c16 * 16;
  u32x4 v = {0, 0, 0, 0};
  if (cb < 2784) {  // cb <= 2768 here (c16 <= 173), so cb+16 <= 2784
    int g = mbase + r;
    const int* pp = (g < npos) ? (posp + 2 * g) : (negp + 2 * (g - npos));
    const u16* ex = emb + (size_t)pp[0] * 2784 + cb;
    const u16* ey = emb + (size_t)(1500 + pp[1]) * 2784 + cb;
    bf16x8 x0 = *(const bf16x8*)ex, x1 = *(const bf16x8*)(ex + 8);
    bf16x8 y0 = *(const bf16x8*)ey, y1 = *(const bf16x8*)(ey + 8);
    unsigned w[4] = {0, 0, 0, 0};
#pragma unroll
    for (int j = 0; j < 8; j++) {
      float p0 = b2f((u16)x0[j]) * b2f((u16)y0[j]) * 0.001953125f;
      float p1 = b2f((u16)x1[j]) * b2f((u16)y1[j]) * 0.001953125f;
      w[j >> 2] |= ((unsigned)q8(p0)) << ((j & 3) * 8);
      w[2 + (j >> 2)] |= ((unsigned)q8(p1)) << ((j & 3) * 8);
    }
    v = (u32x4){w[0], w[1], w[2], w[3]};
  }
  *(u32x4*)(fq + (size_t)r * 2816 + cb) = v;
}

// ---------------------------------------------------------------------------
// fp8 MFMA GEMM (L1): C[M,N] = lrelu(oscale*(A@B) + bias), bf16 out.
// A: M x lda bytes (fp8, K-contig), BT: Npad x ldb bytes. BK=64 (2 sub-steps
// of 16x16x32_fp8_fp8 per barrier). 128x128 tile, 4 waves.
// ---------------------------------------------------------------------------
__global__ __launch_bounds__(256, 2) void mgemm_q(
    const u8* __restrict__ A, const u8* __restrict__ BT,
    const u16* __restrict__ bias, u16* __restrict__ C, int M, int N, int Kpad,
    int lda, int ldb, int ldc, float slope, float oscale) {
  __shared__ u8 As[128 * 64];
  __shared__ u8 Bs[128 * 64];
  const int t = threadIdx.x;
  const int lane = t & 63, wave = t >> 6;
  const int quad = lane >> 4, l16 = lane & 15;
  const int wm = wave >> 1, wn = wave & 1;
  const int m0 = blockIdx.y * 128, n0 = blockIdx.x * 128;

  const int r0 = t >> 2;       // staging row (4 lanes/row, 16B each)
  const int kc = (t & 3) * 16; // byte offset in row

  f32x4 zero4 = {0.f, 0.f, 0.f, 0.f};
  f32x4 acc[4][4];
#pragma unroll
  for (int i = 0; i < 4; i++)
#pragma unroll
    for (int j = 0; j < 4; j++) acc[i][j] = zero4;

  u8* As_w = &As[wave * 1024];
  u8* Bs_w = &Bs[wave * 1024];
  const u8* Ap = A + (size_t)(m0 + r0) * lda + kc;
  const u8* Bp = BT + (size_t)(n0 + r0) * ldb + kc;
  const size_t a64 = (size_t)64 * lda, b64 = (size_t)64 * ldb;

  for (int k0 = 0; k0 < Kpad; k0 += 64) {
    async_ld16(Ap + k0, As_w);
    async_ld16(Ap + a64 + k0, As_w + 4096);
    async_ld16(Bp + k0, Bs_w);
    async_ld16(Bp + b64 + k0, Bs_w + 4096);
    __syncthreads();
#pragma unroll
    for (int s = 0; s < 2; s++) {
      long long af[4], bfr[4];
#pragma unroll
      for (int i = 0; i < 4; i++)
        af[i] = *(const long long*)(&As[(wm * 64 + i * 16 + l16) * 64 +
                                        s * 32 + quad * 8]);
#pragma unroll
      for (int j = 0; j < 4; j++)
        bfr[j] = *(const long long*)(&Bs[(wn * 64 + j * 16 + l16) * 64 +
                                         s * 32 + quad * 8]);
#pragma unroll
      for (int i = 0; i < 4; i++)
#pragma unroll
        for (int j = 0; j < 4; j++)
          acc[i][j] = __builtin_amdgcn_mfma_f32_16x16x32_fp8_fp8(
              af[i], bfr[j], acc[i][j], 0, 0, 0);
    }
    __syncthreads();
  }

#pragma unroll
  for (int j = 0; j < 4; j++) {
    int col = n0 + wn * 64 + j * 16 + l16;
    if (col >= ldc) continue;
    float bv = 0.f;
    if (bias != nullptr && col < N) bv = b2f(bias[col]);
#pragma unroll
    for (int i = 0; i < 4; i++) {
#pragma unroll
      for (int r = 0; r < 4; r++) {
        int row = m0 + wm * 64 + i * 16 + quad * 4 + r;
        if (row >= M) continue;
        float v;
        if (col < N) {
          v = acc[i][j][r] * oscale + bv;
          v = (v > 0.f) ? v : v * slope;
        } else {
          v = 0.f;
        }
        C[(size_t)row * ldc + col] = f2b(v);
      }
    }
  }
}

// ---------------------------------------------------------------------------
// bf16 MFMA GEMM (L2/L3, unchanged from R11)
// ---------------------------------------------------------------------------
__global__ __launch_bounds__(256, 2) void mgemm(
    const u16* __restrict__ A, const u16* __restrict__ BT,
    const u16* __restrict__ bias, u16* __restrict__ C, int M, int N, int Kpad,
    int lda, int ldb, int ldc, float slope) {
  __shared__ u16 As[128 * 32];
  __shared__ u16 Bs[128 * 32];
  const int t = threadIdx.x;
  const int lane = t & 63, wave = t >> 6;
  const int quad = lane >> 4, l16 = lane & 15;
  const int wm = wave >> 1, wn = wave & 1;
  const int m0 = blockIdx.y * 128, n0 = blockIdx.x * 128;

  const int r0 = t >> 2;
  const int kc = (t & 3) * 8;

  f32x4 zero4 = {0.f, 0.f, 0.f, 0.f};
  f32x4 acc[4][4];
#pragma unroll
  for (int i = 0; i < 4; i++)
#pragma unroll
    for (int j = 0; j < 4; j++) acc[i][j] = zero4;

  u16* As_w = &As[wave * 512];
  u16* Bs_w = &Bs[wave * 512];
  const u16* Ap = A + (size_t)(m0 + r0) * lda + kc;
  const u16* Bp = BT + (size_t)(n0 + r0) * ldb + kc;
  const size_t a64 = (size_t)64 * lda, b64 = (size_t)64 * ldb;

  for (int k0 = 0; k0 < Kpad; k0 += 32) {
    async_ld16(Ap + k0, As_w);
    async_ld16(Ap + a64 + k0, As_w + 2048);
    async_ld16(Bp + k0, Bs_w);
    async_ld16(Bp + b64 + k0, Bs_w + 2048);
    __syncthreads();
    bf16x8 af[4], bfr[4];
#pragma unroll
    for (int i = 0; i < 4; i++)
      af[i] = *(const bf16x8*)(&As[(wm * 64 + i * 16 + l16) * 32 + quad * 8]);
#pragma unroll
    for (int j = 0; j < 4; j++)
      bfr[j] = *(const bf16x8*)(&Bs[(wn * 64 + j * 16 + l16) * 32 + quad * 8]);
#pragma unroll
    for (int i = 0; i < 4; i++)
#pragma unroll
      for (int j = 0; j < 4; j++)
        acc[i][j] = __builtin_amdgcn_mfma_f32_16x16x32_bf16(af[i], bfr[j],
                                                            acc[i][j], 0, 0, 0);
    __syncthreads();
  }

#pragma unroll
  for (int j = 0; j < 4; j++) {
    int col = n0 + wn * 64 + j * 16 + l16;
    if (col >= ldc) continue;
    float bv = 0.f;
    if (bias != nullptr && col < N) bv = b2f(bias[col]);
#pragma unroll
    for (int i = 0; i < 4; i++) {
#pragma unroll
      for (int r = 0; r < 4; r++) {
        int row = m0 + wm * 64 + i * 16 + quad * 4 + r;
        if (row >= M) continue;
        float v;
        if (col < N) {
          v = acc[i][j][r] + bv;
          v = (v > 0.f) ? v : v * slope;
        } else {
          v = 0.f;
        }
        C[(size_t)row * ldc + col] = f2b(v);
      }
    }
  }
}

// ---------------------------------------------------------------------------
// f32 VALU GEMM (front end)
// ---------------------------------------------------------------------------
__global__ __launch_bounds__(256) void vgemm_f(
    const float* __restrict__ A, const float* __restrict__ BT,
    const float* __restrict__ bias, float* __restrict__ C, int M, int N, int K,
    int lda, int ldb, int ldc) {
  __shared__ float As[16 * 66];
  __shared__ float Bs[64 * 66];
  const int t = threadIdx.x;
  const int m0 = blockIdx.y * 16, n0 = blockIdx.x * 64;
  const int tx = t & 63, ty = t >> 6;
  float acc[4] = {0.f, 0.f, 0.f, 0.f};
  for (int k0 = 0; k0 < K; k0 += 64) {
    for (int idx = t; idx < 16 * 64; idx += 256) {
      int r = idx >> 6, k = idx & 63;
      int m = m0 + r, kk = k0 + k;
      As[r * 66 + k] = (m < M && kk < K) ? A[(size_t)m * lda + kk] : 0.f;
    }
    for (int idx = t; idx < 64 * 64; idx += 256) {
      int nr = idx >> 6, k = idx & 63;
      int nn = n0 + nr, kk = k0 + k;
      Bs[nr * 66 + k] = (nn < N && kk < K) ? BT[(size_t)nn * ldb + kk] : 0.f;
    }
    __syncthreads();
#pragma unroll 8
    for (int k = 0; k < 64; k++) {
      float b = Bs[tx * 66 + k];
#pragma unroll
      for (int q = 0; q < 4; q++) acc[q] += As[(ty * 4 + q) * 66 + k] * b;
    }
    __syncthreads();
  }
  int col = n0 + tx;
  if (col >= N) return;
  float bv = (bias != nullptr) ? bias[col] : 0.f;
#pragma unroll
  for (int q = 0; q < 4; q++) {
    int row = m0 + ty * 4 + q;
    if (row < M) C[(size_t)row * ldc + col] = acc[q] + bv;
  }
}

__global__ void k_zero2(int* __restrict__ a, int* __restrict__ b, int n) {
  int tid = blockIdx.x * 256 + threadIdx.x;
  if (tid < n) { a[tid] = 0; b[tid] = 0; }
}

// ---------------------------------------------------------------------------
// GAT
// ---------------------------------------------------------------------------
__global__ void k_edge_e(const float* __restrict__ xl,
                         const float* __restrict__ xr,
                         const int* __restrict__ ei,
                         const float* __restrict__ att, float* __restrict__ e,
                         int E, int Etot) {
  __shared__ float attf[1024];
  int t = threadIdx.x;
  for (int i = t; i < 1024; i += 256) attf[i] = att[i];
  __syncthreads();
  int lane = t & 63;
  int eid = blockIdx.x * 4 + (t >> 6);
  if (eid >= Etot) return;
  int src = (eid < E) ? ei[eid] : (eid - E);
  int dst = (eid < E) ? ei[E + eid] : (eid - E);
  const float* pl = xl + (size_t)src * 1024;
  const float* pr = xr + (size_t)dst * 1024;
#pragma unroll
  for (int h = 0; h < 8; h++) {
    float a0 = pl[h * 128 + lane] + pr[h * 128 + lane];
    float a1 = pl[h * 128 + 64 + lane] + pr[h * 128 + 64 + lane];
    a0 = (a0 > 0.f) ? a0 : 0.2f * a0;
    a1 = (a1 > 0.f) ? a1 : 0.2f * a1;
    float p = a0 * attf[h * 128 + lane] + a1 * attf[h * 128 + 64 + lane];
#pragma unroll
    for (int off = 32; off; off >>= 1) p += __shfl_xor(p, off);
    if (lane == 0) e[(size_t)eid * 8 + h] = p;
  }
}

__global__ void k_count(const int* __restrict__ ei, int* __restrict__ cnt,
                        int E, int Etot) {
  int tid = blockIdx.x * 256 + threadIdx.x;
  if (tid >= Etot) return;
  int dst = (tid < E) ? ei[E + tid] : (tid - E);
  atomicAdd(&cnt[dst], 1);
}

__global__ void k_scan(const int* __restrict__ cnt, int* __restrict__ rowstart,
                       int Nn) {
  __shared__ int part[257];
  int t = threadIdx.x;
  int chunk = (Nn + 255) / 256;
  int b = t * chunk;
  int en = b + chunk; if (en > Nn) en = Nn;
  int s = 0;
  for (int i = b; i < en; i++) s += cnt[i];
  part[t] = s;
  __syncthreads();
  if (t == 0) {
    int acc = 0;
    for (int i = 0; i < 256; i++) { int v = part[i]; part[i] = acc; acc += v; }
    part[256] = acc;
  }
  __syncthreads();
  int run = part[t];
  for (int i = b; i < en; i++) { rowstart[i] = run; run += cnt[i]; }
  if (t == 0) rowstart[Nn] = part[256];
}

__global__ void k_scatter(const int* __restrict__ ei,
                          const int* __restrict__ rowstart,
                          int* __restrict__ cur, int* __restrict__ csr, int E,
                          int Etot) {
  int tid = blockIdx.x * 256 + threadIdx.x;
  if (tid >= Etot) return;
  int dst = (tid < E) ? ei[E + tid] : (tid - E);
  int p = atomicAdd(&cur[dst], 1);
  unsigned idx = (unsigned)(rowstart[dst] + p);
  if (idx < (unsigned)Etot) csr[idx] = tid;
}

__global__ void k_softmax(const float* __restrict__ e,
                          const int* __restrict__ csr,
                          const int* __restrict__ rowstart,
                          float* __restrict__ wgt, int Nn, int Etot) {
  int t = threadIdx.x;
  int lane = t & 63;
  int d = blockIdx.x * 4 + (t >> 6);
  if (d >= Nn) return;
  int rs = rowstart[d], re = rowstart[d + 1];
  for (int h = 0; h < 8; h++) {
    float mx = -3.0e38f;
    for (int i = rs + lane; i < re; i += 64) {
      unsigned eid = (unsigned)csr[i];
      if (eid < (unsigned)Etot) mx = fmaxf(mx, e[(size_t)eid * 8 + h]);
    }
#pragma unroll
    for (int off = 32; off; off >>= 1) mx = fmaxf(mx, __shfl_xor(mx, off));
    if (mx < -1.0e37f) mx = 0.f;
    float s = 0.f;
    for (int i = rs + lane; i < re; i += 64) {
      unsigned eid = (unsigned)csr[i];
      if (eid < (unsigned)Etot) s += expf(e[(size_t)eid * 8 + h] - mx);
    }
#pragma unroll
    for (int off = 32; off; off >>= 1) s += __shfl_xor(s, off);
    float inv = (s > 0.f) ? 1.f / s : 0.f;
    for (int i = rs + lane; i < re; i += 64) {
      unsigned eid = (unsigned)csr[i];
      if (eid < (unsigned)Etot)
        wgt[(size_t)eid * 8 + h] = expf(e[(size_t)eid * 8 + h] - mx) * inv;
    }
  }
}

__global__ void k_aggregate(const float* __restrict__ wgt,
                            const float* __restrict__ xl,
                            const int* __restrict__ ei,
                            const int* __restrict__ csr,
                            const int* __restrict__ rowstart,
                            const float* __restrict__ gbias,
                            float* __restrict__ res, int E, int Etot) {
  int d = blockIdx.x;
  int t = threadIdx.x;
  int c = t & 127, hb = t >> 7;
  int rs = rowstart[d], re = rowstart[d + 1];
  float acc[4] = {0.f, 0.f, 0.f, 0.f};
  for (int i = rs; i < re; i++) {
    unsigned eid = (unsigned)csr[i];
    if (eid >= (unsigned)Etot) continue;
    int src = (eid < (unsigned)E) ? ei[eid] : (int)(eid - E);
    const float* px = xl + (size_t)src * 1024 + hb * 512 + c;
    const float* pw = wgt + (size_t)eid * 8 + hb * 4;
#pragma unroll
    for (int q = 0; q < 4; q++) acc[q] += pw[q] * px[q * 128];
  }
#pragma unroll
  for (int q = 0; q < 4; q++) {
    int idx = (hb * 4 + q) * 128 + c;
    res[(size_t)d * 1024 + idx] = acc[q] + gbias[idx];
  }
}

// ---------------------------------------------------------------------------
// CNN: f32 in, f32 out to d_out (stride 2778), bf16 emb (stride 2784, padded)
// ---------------------------------------------------------------------------
__global__ void k_cnn(const float* __restrict__ res,
                      const float* __restrict__ cw1, const float* __restrict__ cb1,
                      const float* __restrict__ cw4, const float* __restrict__ cb4,
                      const float* __restrict__ cw16, const float* __restrict__ cb16,
                      const float* __restrict__ cw32, const float* __restrict__ cb32,
                      float* __restrict__ outc, u16* __restrict__ emb) {
  __shared__ float xs[1024];
  __shared__ float wc[2544];
  __shared__ float cb[24];
  int t = threadIdx.x, node = blockIdx.x;
  for (int i = t; i < 1024; i += 256) xs[i] = res[(size_t)node * 1024 + i];
  for (int i = t; i < 48; i += 256) wc[i] = cw1[i];
  for (int i = t; i < 192; i += 256) wc[48 + i] = cw4[i];
  for (int i = t; i < 768; i += 256) wc[240 + i] = cw16[i];
  for (int i = t; i < 1536; i += 256) wc[1008 + i] = cw32[i];
  if (t < 6) {
    cb[t] = cb1[t];
    cb[6 + t] = cb4[t];
    cb[12 + t] = cb16[t];
    cb[18 + t] = cb32[t];
  }
  __syncthreads();
  for (int o = t; o < 2778; o += 256) {
    int k, W, base, boff, rr;
    if (o < 768)       { k = 1;  W = 128; base = 0;    boff = 0;  rr = o; }
    else if (o < 1518) { k = 4;  W = 125; base = 48;   boff = 6;  rr = o - 768; }
    else if (o < 2196) { k = 16; W = 113; base = 240;  boff = 12; rr = o - 1518; }
    else               { k = 32; W = 97;  base = 1008; boff = 18; rr = o - 2196; }
    int oc = rr / W, wp = rr - oc * W;
    const float* wgt = &wc[base + oc * 8 * k];
    float v = cb[boff + oc];
    for (int h = 0; h < 8; h++)
      for (int j = 0; j < k; j++) v += xs[h * 128 + wp + j] * wgt[h * k + j];
    v = fmaxf(v, 0.f);
    outc[(size_t)node * 2778 + o] = v;
    emb[(size_t)node * 2784 + o] = f2b(v);
  }
  if (t < 6) emb[(size_t)node * 2784 + 2778 + t] = 0;
}

// ---------------------------------------------------------------------------
__global__ void k_gemv_sig(const u16* __restrict__ hh3,
                           const u16* __restrict__ w4, float* __restrict__ pred,
                           int M, int K, int ldk) {
  __shared__ float ws[464];
  int t = threadIdx.x;
  for (int i = t; i < K; i += 256) ws[i] = b2f(w4[i]);
  __syncthreads();
  int lane = t & 63;
  int m = blockIdx.x * 4 + (t >> 6);
  if (m >= M) return;
  const u16* p = hh3 + (size_t)m * ldk;
  float s = 0.f;
  for (int i = lane; i < K; i += 64) s += b2f(p[i]) * ws[i];
#pragma unroll
  for (int off = 32; off; off >>= 1) s += __shfl_xor(s, off);
  if (!(s == s)) s = 0.f;
  s = fminf(fmaxf(s, -30.f), 30.f);
  if (lane == 0) pred[m] = 1.f / (1.f + expf(-s));
}

__global__ void k_labels(float* __restrict__ lab, int P) {
  int tid = blockIdx.x * 256 + threadIdx.x;
  if (tid < 2 * P) lab[tid] = (tid < P) ? 1.f : 0.f;
}

__global__ void k_sentinel(float* __restrict__ pred, int M, float val) {
  int tid = blockIdx.x * 256 + threadIdx.x;
  if (tid < M) pred[tid] = val;
}

// ---------------------------------------------------------------------------
extern "C" void kernel_launch(void* const* d_in, const int* in_sizes, int n_in,
                              void* d_out, int out_size, void* d_ws,
                              size_t ws_size, hipStream_t stream) {
  (void)in_sizes; (void)n_in; (void)out_size;
  const int* ei = (const int*)d_in[2];
  const int* posp = (const int*)d_in[3];
  const int* negp = (const int*)d_in[4];

  const int E = 80000, ET = 82300, P = 40000, M = 80000;

  float* outp = (float*)d_out;
  float* outl = outp + 80000;
  float* outc = outp + 160000;

  k_labels<<<(2 * P + 255) / 256, 256, 0, stream>>>(outl, P);

  char* base = (char*)d_ws;
  size_t off = 0;
  auto alloc = [&](size_t bytes) -> void* {
    void* p = base + off;
    off = (off + bytes + 255) & ~(size_t)255;
    return p;
  };
  // front-end f32 copies
  float* mic_f = (float*)alloc((size_t)1500 * 1500 * 4);
  float* dis_f = (float*)alloc((size_t)800 * 800 * 4);
  float* WmT_f = (float*)alloc((size_t)128 * 1500 * 4);
  float* WdT_f = (float*)alloc((size_t)128 * 800 * 4);
  float* WlT_f = (float*)alloc((size_t)1024 * 128 * 4);
  float* WrT_f = (float*)alloc((size_t)1024 * 128 * 4);
  float* bl_f = (float*)alloc(1024 * 4);
  float* br_f = (float*)alloc(1024 * 4);
  float* att_f = (float*)alloc(1024 * 4);
  float* gbias_f = (float*)alloc(1024 * 4);
  float* cw1_f = (float*)alloc(48 * 4);
  float* cb1_f = (float*)alloc(6 * 4);
  float* cw4_f = (float*)alloc(192 * 4);
  float* cb4_f = (float*)alloc(6 * 4);
  float* cw16_f = (float*)alloc(768 * 4);
  float* cb16_f = (float*)alloc(6 * 4);
  float* cw32_f = (float*)alloc(1536 * 4);
  float* cb32_f = (float*)alloc(6 * 4);
  // MLP weights: L1 fp8 (N 1389->1408, K 2778->2816), L2/L3 bf16 as R11
  u8* m1q = (u8*)alloc((size_t)1408 * 2816);
  u16* m2T = (u16*)alloc((size_t)768 * 1408 * 2);
  u16* m3T = (u16*)alloc((size_t)512 * 704 * 2);
  u16* mb1_b = (u16*)alloc(1389 * 2);
  u16* mb2_b = (u16*)alloc(694 * 2);
  u16* mb3_b = (u16*)alloc(463 * 2);
  u16* mw4_b = (u16*)alloc(463 * 2);
  // intermediates
  float* hbuf = (float*)alloc((size_t)2300 * 128 * 4);
  float* xlf = (float*)alloc((size_t)2300 * 1024 * 4);
  float* xrf = (float*)alloc((size_t)2300 * 1024 * 4);
  float* resf = xrf;  // xr dead after k_edge_e
  float* ebuf = (float*)alloc((size_t)ET * 8 * 4);
  float* wbuf = (float*)alloc((size_t)ET * 8 * 4);
  u16* emb = (u16*)alloc((size_t)2300 * 2784 * 2);
  int* cnt = (int*)alloc(2300 * 4);
  int* rowst = (int*)alloc(2304 * 4);
  int* cur = (int*)alloc(2300 * 4);
  int* csr = (int*)alloc((size_t)ET * 4);
  size_t fixed_end = off;

  // chunk: feats_q (R x 2816 u8) + hh1 (R x 1408 bf16) + hh2 (R x 704 bf16)
  const size_t per_row = 2816 + (size_t)1408 * 2 + (size_t)704 * 2;
  size_t avail = (ws_size > fixed_end) ? (ws_size - fixed_end) : 0;
  long long Rll = (long long)(avail / per_row);
  int R = (Rll > M) ? M : (int)Rll;
  R &= ~127;
  if (R > 16256) R = 16256;
  if (fixed_end > ws_size || R < 128) {
    k_sentinel<<<(M + 255) / 256, 256, 0, stream>>>(outp, M, 0.25f);
    return;
  }
  u8* feats_q = (u8*)(base + fixed_end);
  u16* hh1 = (u16*)(feats_q + (size_t)R * 2816);
  u16* hh2 = hh1 + (size_t)R * 1408;

  k_zero2<<<(2300 + 255) / 256, 256, 0, stream>>>(cnt, cur, 2300);

  // ---- canonicalize inputs ----
  cvt_f<<<(2250000 + 255) / 256, 256, 0, stream>>>(d_in[0], mic_f, 2250000);
  cvt_f<<<(640000 + 255) / 256, 256, 0, stream>>>(d_in[1], dis_f, 640000);
  cvt_f_t<<<(192000 + 255) / 256, 256, 0, stream>>>(d_in[6], WmT_f, 1500, 128);
  cvt_f_t<<<(102400 + 255) / 256, 256, 0, stream>>>(d_in[7], WdT_f, 800, 128);
  cvt_f_t<<<(131072 + 255) / 256, 256, 0, stream>>>(d_in[8], WlT_f, 128, 1024);
  cvt_f<<<4, 256, 0, stream>>>(d_in[9], bl_f, 1024);
  cvt_f_t<<<(131072 + 255) / 256, 256, 0, stream>>>(d_in[10], WrT_f, 128, 1024);
  cvt_f<<<4, 256, 0, stream>>>(d_in[11], br_f, 1024);
  cvt_f<<<4, 256, 0, stream>>>(d_in[12], att_f, 1024);
  cvt_f<<<4, 256, 0, stream>>>(d_in[13], gbias_f, 1024);
  cvt_f<<<1, 256, 0, stream>>>(d_in[14], cw1_f, 48);
  cvt_f<<<1, 256, 0, stream>>>(d_in[15], cb1_f, 6);
  cvt_f<<<1, 256, 0, stream>>>(d_in[16], cw4_f, 192);
  cvt_f<<<1, 256, 0, stream>>>(d_in[17], cb4_f, 6);
  cvt_f<<<3, 256, 0, stream>>>(d_in[18], cw16_f, 768);
  cvt_f<<<1, 256, 0, stream>>>(d_in[19], cb16_f, 6);
  cvt_f<<<6, 256, 0, stream>>>(d_in[20], cw32_f, 1536);
  cvt_f<<<1, 256, 0, stream>>>(d_in[21], cb32_f, 6);
  // W1 -> fp8 (x64), transposed+padded; W2/W3 bf16 as before
  cvt_q_tt<<<dim3((2816 + 31) / 32, (1408 + 31) / 32), 256, 0, stream>>>(
      d_in[22], m1q, 2778, 1389, 2816, 1408, 64.f);
  cvt_b<<<(1389 + 255) / 256, 256, 0, stream>>>(d_in[23], mb1_b, 1389);
  cvt_b_tt<<<dim3((1408 + 31) / 32, (768 + 31) / 32), 256, 0, stream>>>(
      d_in[24], m2T, 1389, 694, 1408, 768);
  cvt_b<<<(694 + 255) / 256, 256, 0, stream>>>(d_in[25], mb2_b, 694);
  cvt_b_tt<<<dim3((704 + 31) / 32, (512 + 31) / 32), 256, 0, stream>>>(
      d_in[26], m3T, 694, 463, 704, 512);
  cvt_b<<<(463 + 255) / 256, 256, 0, stream>>>(d_in[27], mb3_b, 463);
  cvt_b<<<(463 + 255) / 256, 256, 0, stream>>>(d_in[28], mw4_b, 463);

  // ---- front end ----
  vgemm_f<<<dim3(2, 94), 256, 0, stream>>>(mic_f, WmT_f, nullptr, hbuf, 1500,
                                           128, 1500, 1500, 1500, 128);
  vgemm_f<<<dim3(2, 50), 256, 0, stream>>>(dis_f, WdT_f, nullptr,
                                           hbuf + (size_t)1500 * 128, 800, 128,
                                           800, 800, 800, 128);
  vgemm_f<<<dim3(16, 144), 256, 0, stream>>>(hbuf, WlT_f, bl_f, xlf, 2300,
                                             1024, 128, 128, 128, 1024);
  vgemm_f<<<dim3(16, 144), 256, 0, stream>>>(hbuf, WrT_f, br_f, xrf, 2300,
                                             1024, 128, 128, 128, 1024);

  k_edge_e<<<(ET + 3) / 4, 256, 0, stream>>>(xlf, xrf, ei, att_f, ebuf, E, ET);
  k_count<<<(ET + 255) / 256, 256, 0, stream>>>(ei, cnt, E, ET);
  k_scan<<<1, 256, 0, stream>>>(cnt, rowst, 2300);
  k_scatter<<<(ET + 255) / 256, 256, 0, stream>>>(ei, rowst, cur, csr, E, ET);
  k_softmax<<<(2300 + 3) / 4, 256, 0, stream>>>(ebuf, csr, rowst, wbuf, 2300, ET);
  k_aggregate<<<2300, 256, 0, stream>>>(wbuf, xlf, ei, csr, rowst, gbias_f,
                                        resf, E, ET);

  k_cnn<<<2300, 256, 0, stream>>>(resf, cw1_f, cb1_f, cw4_f, cb4_f, cw16_f,
                                  cb16_f, cw32_f, cb32_f, outc, emb);

  // ---- MLP: fp8 L1 + bf16 L2/L3, chunked ----
  for (int c0 = 0; c0 < M; c0 += R) {
    int rows = (M - c0 < R) ? (M - c0) : R;
    int gby = (rows + 127) / 128;
    k_feats_q<<<((size_t)rows * 176 + 255) / 256, 256, 0, stream>>>(
        emb, posp, negp, P, c0, rows, feats_q);
    mgemm_q<<<dim3(11, gby), 256, 0, stream>>>(feats_q, m1q, mb1_b, hh1, rows,
                                               1389, 2816, 2816, 2816, 1408,
                                               0.01f, 8.f);
    mgemm<<<dim3(6, gby), 256, 0, stream>>>(hh1, m2T, mb2_b, hh2, rows, 694,
                                            1408, 1408, 1408, 704, 0.01f);
    mgemm<<<dim3(4, gby), 256, 0, stream>>>(hh2, m3T, mb3_b, hh1, rows, 463,
                                            704, 704, 704, 480, 0.01f);
    k_gemv_sig<<<(rows + 3) / 4, 256, 0, stream>>>(hh1, mw4_b, outp + c0, rows,
                                                   463, 480);
  }
}